// Round 2
// 2099.363 us; speedup vs baseline: 1.3240x; 1.3240x over previous
//
#include <hip/hip_runtime.h>
#include <math.h>

// Problem constants
#define NB 16
#define NT 2048
#define ND 512
#define NK 8192
#define NN (NB*NT)      // 32768 rows
#define NTOP 8
#define SCALE_SIM 0.044194173824159216f   // 1/sqrt(512)

// K2 tiling
#define CHUNK 2048      // cols per workgroup (4 chunks cover NK)
#define CT 128          // col tile
#define BK 32           // k-step

typedef __attribute__((ext_vector_type(8))) short bf16x8;   // 8 bf16 = 4 VGPR
typedef __attribute__((ext_vector_type(4))) float f32x4;    // MFMA acc / native float4

// fp32 -> bf16 round-to-nearest-even
__device__ __forceinline__ unsigned int f2bf(float f) {
  unsigned int u = __float_as_uint(f);
  return (u + 0x7FFFu + ((u >> 16) & 1u)) >> 16;
}

// async global->LDS, 16B per lane; lds dst = wave-uniform base + lane*16
__device__ __forceinline__ void gl16(const void* g, void* l) {
  __builtin_amdgcn_global_load_lds((const __attribute__((address_space(1))) void*)g,
                                   (__attribute__((address_space(3))) void*)l, 16, 0, 0);
}

// monotone f32 -> sortable u32 (larger float => larger unsigned)
__device__ __forceinline__ unsigned sortable(float f) {
  unsigned fb = __float_as_uint(f);
  unsigned sx = (unsigned)((int)fb >> 31);
  return fb ^ (sx | 0x80000000u);
}

// ---------------- K1: bf16 conversion + ||c||^2 ----------------
__global__ void prep_kernel(const float* __restrict__ q,
                            const float* __restrict__ cbbase,
                            const int* __restrict__ modality,
                            ushort* __restrict__ q_bf, ushort* __restrict__ cb_bf,
                            float* __restrict__ cc) {
  int gw = (blockIdx.x * blockDim.x + threadIdx.x) >> 6;
  int lane = threadIdx.x & 63;
  if (gw < NN) {
    const float* src = q + (size_t)gw * ND + lane * 8;
    float4 v0 = ((const float4*)src)[0];
    float4 v1 = ((const float4*)src)[1];
    uint4 o;
    o.x = f2bf(v0.x) | (f2bf(v0.y) << 16);
    o.y = f2bf(v0.z) | (f2bf(v0.w) << 16);
    o.z = f2bf(v1.x) | (f2bf(v1.y) << 16);
    o.w = f2bf(v1.z) | (f2bf(v1.w) << 16);
    *(uint4*)(q_bf + (size_t)gw * ND + lane * 8) = o;
  } else {
    int r = gw - NN;
    const float* cb = cbbase + (size_t)(*modality) * ((size_t)NK * ND);
    const float* src = cb + (size_t)r * ND + lane * 8;
    float4 v0 = ((const float4*)src)[0];
    float4 v1 = ((const float4*)src)[1];
    uint4 o;
    o.x = f2bf(v0.x) | (f2bf(v0.y) << 16);
    o.y = f2bf(v0.z) | (f2bf(v0.w) << 16);
    o.z = f2bf(v1.x) | (f2bf(v1.y) << 16);
    o.w = f2bf(v1.z) | (f2bf(v1.w) << 16);
    *(uint4*)(cb_bf + (size_t)r * ND + lane * 8) = o;
    float s = 0.f;
    s = fmaf(v0.x, v0.x, s); s = fmaf(v0.y, v0.y, s);
    s = fmaf(v0.z, v0.z, s); s = fmaf(v0.w, v0.w, s);
    s = fmaf(v1.x, v1.x, s); s = fmaf(v1.y, v1.y, s);
    s = fmaf(v1.z, v1.z, s); s = fmaf(v1.w, v1.w, s);
#pragma unroll
    for (int off = 32; off > 0; off >>= 1) s += __shfl_down(s, off);
    if (lane == 0) cc[r] = s;
  }
}

// ---------------- K2: bf16 MFMA sim + in-register top-12 + fused coalesced zero ----------------
// grid 1024 = 256 row-blocks x 4 col-chunks; 256 threads = 4 waves, wave tile 64x64.
// SWAPPED mfma operands: acc[i][j] = mfma(b[i], a[j]) puts q-row = lane&15 in the
// C/D col slot -> each lane owns q-rows (wr*64 + j*16 + m) entirely in registers.
// Selection = branchless sorted-insert chain on packed sortable u32 (key21|invcol11).
// Merge: BOTH waves of a row-half (wc=0,1) contribute 8 streams -> chunk top-16
// (round-0 candidate semantics; the wc==0 wave does the merge, reading both slabs).
__global__ __launch_bounds__(256, 2)
void sim_topk_kernel(const ushort* __restrict__ q_bf, const ushort* __restrict__ cb_bf,
                     const float* __restrict__ cc, float* __restrict__ out_w,
                     unsigned* __restrict__ cand) {
  __shared__ ushort A_lds[2][128 * 32];         // 16 KB  [buf][row][k]
  __shared__ ushort B_lds[2][128 * 32];         // 16 KB  [buf][col][k]
  __shared__ __align__(16) float cc_lds[CHUNK]; //  8 KB  chunk ||c||^2
  __shared__ unsigned mg[4][64][12];            // 12 KB  per-wave merge scratch

  const int rb = blockIdx.x >> 2, ch = blockIdx.x & 3;
  const int r0 = rb * 128, ccol0 = ch * CHUNK;
  const int t = threadIdx.x, lane = t & 63, w = t >> 6;
  const int wr = w >> 1, wc = w & 1;           // wave quadrant in 128x128 tile
  const int m = lane & 15, quad = lane >> 4;   // MFMA lane decomposition

  // stage cc chunk into LDS (first consumed after tile-0's 16 k-step barriers)
  {
    const f32x4* src = (const f32x4*)(cc + ccol0);
    *(f32x4*)&cc_lds[t * 8]     = src[t * 2];
    *(f32x4*)&cc_lds[t * 8 + 4] = src[t * 2 + 1];
  }

  // XOR-swizzled staging: global source pre-swizzled (lane&3 ^ (lane>>3)&3),
  // LDS dest stays linear (global_load_lds requirement); frag reads apply the
  // matching quad ^ (m>>1)&3 -> each 16-lane phase spreads over all 8 bank-quads.
  const int sl = ((lane & 3) ^ ((lane >> 3) & 3)) * 8;
  const ushort* gA = q_bf + (size_t)(r0 + w * 32 + (lane >> 2)) * ND + sl;
  const ushort* gB = cb_bf + (size_t)(ccol0 + w * 32 + (lane >> 2)) * ND + sl;

  const int swq = quad ^ ((m >> 1) & 3);
  const int aoff = (wr * 64 + m) * 32 + swq * 8;   // + j*512 per q-row-frag
  const int boff = (wc * 64 + m) * 32 + swq * 8;   // + i*512 per cb-col-frag

  // per-lane top-12 chains, one per owned q-row (j=0..3), packed u32, sorted desc
  unsigned tl[4][12];
#pragma unroll
  for (int j = 0; j < 4; ++j)
#pragma unroll
    for (int s = 0; s < 12; ++s) tl[j][s] = 0u;

  const f32x4 z4 = (f32x4){0.f, 0.f, 0.f, 0.f};

  // prologue: stage (tile=0, s=0) into buffer 0
  {
    ushort* lA = &A_lds[0][w * 1024];
    ushort* lB = &B_lds[0][w * 1024];
    gl16(gA, lA);
    gl16(gA + 16 * ND, lA + 512);
    gl16(gB, lB);
    gl16(gB + 16 * ND, lB + 512);
  }

  for (int tile = 0; tile < 16; ++tile) {
    f32x4 acc[4][4];
#pragma unroll
    for (int i = 0; i < 4; ++i)
#pragma unroll
      for (int j = 0; j < 4; ++j) acc[i][j] = (f32x4){0.f, 0.f, 0.f, 0.f};

#pragma unroll
    for (int s = 0; s < ND / BK; ++s) {        // 16 k-steps
      __syncthreads();                          // buf[s&1] staged & visible
      {
        int ntile = (s < 15) ? tile : tile + 1;
        if (ntile < 16) {
          int ns = (s + 1) & 15;
          int nb = (s + 1) & 1;
          ushort* lA = &A_lds[nb][w * 1024];
          ushort* lB = &B_lds[nb][w * 1024];
          const ushort* gBt = gB + (size_t)ntile * CT * ND;
          gl16(gA + ns * 32, lA);
          gl16(gA + ns * 32 + 16 * ND, lA + 512);
          gl16(gBt + ns * 32, lB);
          gl16(gBt + ns * 32 + 16 * ND, lB + 512);
        }
      }
      const ushort* Ab = &A_lds[s & 1][0];
      const ushort* Bb = &B_lds[s & 1][0];
      bf16x8 a[4], b[4];
#pragma unroll
      for (int j = 0; j < 4; ++j) a[j] = *(const bf16x8*)&Ab[aoff + j * 512];
#pragma unroll
      for (int i = 0; i < 4; ++i) b[i] = *(const bf16x8*)&Bb[boff + i * 512];
#pragma unroll
      for (int i = 0; i < 4; ++i)
#pragma unroll
        for (int j = 0; j < 4; ++j)
          acc[i][j] = __builtin_amdgcn_mfma_f32_16x16x32_bf16(b[i], a[j], acc[i][j], 0, 0, 0);
    }

    // fused zero of this wg's out_w slab (issue early; retires under selection VALU)
    {
      size_t rowbase = (size_t)(r0 + tile * 8) * NK + ccol0;
#pragma unroll
      for (int ii = 0; ii < 16; ++ii) {
        int s = ii * 256 + t;                   // 0..4095 over 8 rows x 512 float4
        f32x4* zp = (f32x4*)(out_w + rowbase + (size_t)(s >> 9) * NK + (size_t)(s & 511) * 4);
        *zp = z4;                               // cached: full-line writes, no nt-RMW
      }
    }

    // in-register selection: key = 2*acc - cc (rank-equivalent to -dist^2 per row);
    // cb-col (within chunk) = tile*CT + wc*64 + i*16 + quad*4 + r
    const int cb0 = tile * CT + wc * 64 + quad * 4;
    const int invb = 2047 - cb0;
#pragma unroll
    for (int i = 0; i < 4; ++i) {
      f32x4 cq = *(const f32x4*)&cc_lds[cb0 + i * 16];
#pragma unroll
      for (int r = 0; r < 4; ++r) {
#pragma unroll
        for (int j = 0; j < 4; ++j) {
          float key = fmaf(2.f, acc[i][j][r], -cq[r]);
          unsigned c = (sortable(key) & 0xFFFFF800u) | (unsigned)(invb - (i * 16 + r));
#pragma unroll
          for (int s2 = 0; s2 < 12; ++s2) {     // branchless compare-exchange chain
            unsigned hi = tl[j][s2] > c ? tl[j][s2] : c;  // v_max_u32
            unsigned lo = tl[j][s2] > c ? c : tl[j][s2];  // v_min_u32
            tl[j][s2] = hi; c = lo;
          }
        }
      }
    }
  }

  // merge: per row, 8 streams (2 wc-halves x 4 quads) x 12 -> chunk top-16 -> cand.
  // Only the wc==0 wave of each row-half merges (reads both waves' mg slabs);
  // cand slots are therefore written exactly once per (row, chunk).
#pragma unroll
  for (int j = 0; j < 4; ++j) {
    __syncthreads();                            // protect mg reuse across j
#pragma unroll
    for (int s = 0; s < 12; ++s) mg[w][lane][s] = tl[j][s];
    __syncthreads();
    if (wc == 0 && lane < 16) {
      unsigned t16[16];
#pragma unroll
      for (int s = 0; s < 16; ++s) t16[s] = 0u;
#pragma unroll 1
      for (int h = 0; h < 2; ++h) {
#pragma unroll 1
        for (int q = 0; q < 4; ++q) {
#pragma unroll 1
          for (int s = 0; s < 12; ++s) {
            unsigned c = mg[wr * 2 + h][q * 16 + lane][s];
#pragma unroll
            for (int s2 = 0; s2 < 16; ++s2) {
              unsigned hi = t16[s2] > c ? t16[s2] : c;
              unsigned lo = t16[s2] > c ? c : t16[s2];
              t16[s2] = hi; c = lo;
            }
          }
        }
      }
      size_t base = (size_t)(r0 + wr * 64 + j * 16 + lane) * 64 + ch * 16;
#pragma unroll
      for (int s = 0; s < 16; ++s) cand[base + s] = t16[s];
    }
  }
}

// ---------------- K3: merge, exact fp32 re-score top-12, top-8 softmax, outputs ----------------
__global__ __launch_bounds__(256, 4)
void finalize_kernel(const float* __restrict__ q, const float* __restrict__ comp,
                     const float* __restrict__ cbbase, const float* __restrict__ logtemp,
                     const int* __restrict__ modality, const float* __restrict__ cc,
                     const unsigned* __restrict__ cand,
                     float* __restrict__ out_r, float* __restrict__ out_w) {
  __shared__ int ssel[4][12];
  const int w = threadIdx.x >> 6, lane = threadIdx.x & 63;
  const int r = blockIdx.x * 4 + w;
  const float* cb = cbbase + (size_t)(*modality) * ((size_t)NK * ND);

  // candidates: packed u32 = key21 | invcol11; chunk = lane>>4
  unsigned u = cand[(size_t)r * 64 + lane];
  unsigned kp = u >> 11;
  int ci = ((lane >> 4) << 11) + (2047 - (int)(u & 0x7FFu));   // global codebook col
  int rank = 0;
  for (int j = 0; j < 64; ++j) {
    unsigned kj = (unsigned)__builtin_amdgcn_readlane((int)kp, j);
    int cj = (int)__builtin_amdgcn_readlane(ci, j);
    rank += (kj > kp || (kj == kp && cj < ci)) ? 1 : 0;        // lower col wins ties
  }
  if (rank < 12) ssel[w][rank] = ci;
  __syncthreads();

  // exact fp32 re-score: 4 lanes per candidate, 128 dims each
  const int c = lane >> 2, part = lane & 3;
  const int cidx = ssel[w][c < 12 ? c : 11];
  float dot = 0.f;
  {
    const float4* qv = (const float4*)(q + (size_t)r * ND) + part * 32;
    const float4* cv = (const float4*)(cb + (size_t)cidx * ND) + part * 32;
#pragma unroll 8
    for (int i = 0; i < 32; ++i) {
      float4 a = qv[i], b = cv[i];
      dot = fmaf(a.x, b.x, dot); dot = fmaf(a.y, b.y, dot);
      dot = fmaf(a.z, b.z, dot); dot = fmaf(a.w, b.w, dot);
    }
  }
  dot += __shfl_xor(dot, 1);
  dot += __shfl_xor(dot, 2);
  float key = fmaf(2.f, dot, -cc[cidx]);   // -dist^2 + qq (qq cancels in softmax)

  // broadcast 12 (key, idx) to all lanes
  float k12[12]; int i12[12];
#pragma unroll
  for (int j = 0; j < 12; ++j) {
    k12[j] = __shfl(key, j * 4);
    i12[j] = __shfl(cidx, j * 4);
  }
  // exact rank among 12 (tie -> lower index, matching lax.top_k)
  int rk = 0;
#pragma unroll
  for (int j = 0; j < 12; ++j)
    rk += (k12[j] > key || (k12[j] == key && i12[j] < cidx)) ? 1 : 0;
  bool sel = (part == 0) && (c < 12) && (rk < NTOP);

  // softmax over the exact top-8
  float at = __expf(*logtemp) * (2.f - comp[r >> 11]);
  float mx = -INFINITY;
#pragma unroll
  for (int j = 0; j < 12; ++j) mx = fmaxf(mx, k12[j]);
  float e = sel ? __expf((key - mx) * (SCALE_SIM / at)) : 0.f;
  float es = e;
#pragma unroll
  for (int off = 32; off > 0; off >>= 1) es += __shfl_xor(es, off);
  float wgt = e / es;
  if (sel) out_w[(size_t)r * NK + cidx] = wgt;   // slab pre-zeroed by K2

  // retrieved = sum_j w_j * cb[idx_j]; non-selected have w==0 exactly
  float w12[12];
#pragma unroll
  for (int j = 0; j < 12; ++j) w12[j] = __shfl(wgt, j * 4);
  float4 a0 = make_float4(0.f, 0.f, 0.f, 0.f), a1 = a0;
  const float4* cb4 = (const float4*)cb;
#pragma unroll
  for (int j = 0; j < 12; ++j) {
    const float4* cp = cb4 + (size_t)i12[j] * (ND / 4) + lane * 2;
    float ww = w12[j];
    float4 c0v = cp[0], c1v = cp[1];
    a0.x = fmaf(ww, c0v.x, a0.x); a0.y = fmaf(ww, c0v.y, a0.y);
    a0.z = fmaf(ww, c0v.z, a0.z); a0.w = fmaf(ww, c0v.w, a0.w);
    a1.x = fmaf(ww, c1v.x, a1.x); a1.y = fmaf(ww, c1v.y, a1.y);
    a1.z = fmaf(ww, c1v.z, a1.z); a1.w = fmaf(ww, c1v.w, a1.w);
  }
  float4* orp = (float4*)(out_r + (size_t)r * ND) + lane * 2;
  orp[0] = a0; orp[1] = a1;
}

extern "C" void kernel_launch(void* const* d_in, const int* in_sizes, int n_in,
                              void* d_out, int out_size, void* d_ws, size_t ws_size,
                              hipStream_t stream) {
  (void)in_sizes; (void)n_in; (void)out_size; (void)ws_size;
  const float* q        = (const float*)d_in[0];
  const float* comp     = (const float*)d_in[1];
  const float* cbbase   = (const float*)d_in[2];
  const float* logtemp  = (const float*)d_in[3];
  const int*   modality = (const int*)d_in[4];
  // d_in[5] = top_k (== 8, compile-time)

  float* out_r = (float*)d_out;
  float* out_w = out_r + (size_t)NN * ND;

  // workspace layout (~50.4 MB)
  ushort*   q_bf  = (ushort*)d_ws;                         // 33,554,432 B
  ushort*   cb_bf = q_bf + (size_t)NN * ND;                //  8,388,608 B
  float*    ccw   = (float*)(cb_bf + (size_t)NK * ND);     //     32,768 B
  unsigned* cand  = (unsigned*)(ccw + NK);                 //  8,388,608 B

  prep_kernel<<<dim3((NN + NK) / 4), dim3(256), 0, stream>>>(q, cbbase, modality, q_bf, cb_bf, ccw);
  sim_topk_kernel<<<dim3((NN / 128) * 4), dim3(256), 0, stream>>>(q_bf, cb_bf, ccw, out_w, cand);
  finalize_kernel<<<dim3(NN / 4), dim3(256), 0, stream>>>(q, comp, cbbase, logtemp, modality, ccw,
                                                          cand, out_r, out_w);
}